// Round 15
// baseline (101.580 us; speedup 1.0000x reference)
//
#include <hip/hip_runtime.h>
#include <hip/hip_bf16.h>
#include <hip/hip_cooperative_groups.h>

namespace cg = cooperative_groups;

// Problem constants (fixed by setup_inputs):
//   x: (64, 8192) f32   weight: (8192, 2048) f32
//   random_numbers: (4,) int (int32 or int64 storage, values in [1, 2^20))
//   y: (64, 8192) f32
#define K_FULL   8192
#define M_ROWS   64
#define N_OUT    8192
#define N_COMP   2048
#define P_MERS   2147483647

// ws layout: [0, 256KB) : xcF bf16, fragment-major:
//   xcF[(s*4 + g)*512 + lane*8 + e] = xc[g*16 + (lane&15)][s*32 + (lane>>4)*8 + e]
//   (s = k-step 0..63, g = m-group 0..3) -> every A-fragment load is 64x16B contiguous.

typedef __attribute__((ext_vector_type(8))) short bf16x8;
typedef __attribute__((ext_vector_type(4))) float f32x4;

__device__ __forceinline__ short f2bfs(float f) {
    __hip_bfloat16 h = __float2bfloat16(f);
    return *reinterpret_cast<short*>(&h);
}
__device__ __forceinline__ unsigned int pk2bf(float a, float b) {
    return (unsigned int)(unsigned short)f2bfs(a)
         | ((unsigned int)(unsigned short)f2bfs(b) << 16);
}

// Async global->LDS DMA, 16B per lane (dest = wave-uniform base + lane*16).
#define GLL(g, l) __builtin_amdgcn_global_load_lds(                          \
    (const __attribute__((address_space(1))) unsigned int*)(g),             \
    (__attribute__((address_space(3))) unsigned int*)(l), 16, 0, 0)

__device__ __forceinline__ int hash_col(int j, int rn0, int rn1, int rn2, int rn3) {
    if (rn1 == 0 && rn3 == 0) {
        // int64 storage (JAX x64 on): exact hash; Mersenne fold (2^31 === 1 mod P)
        unsigned long long xx = (unsigned long long)(unsigned int)rn0 * (unsigned int)j
                              + (unsigned long long)(unsigned int)rn2;
        unsigned long long t = (xx & (unsigned long long)P_MERS) + (xx >> 31);
        if (t >= (unsigned long long)P_MERS) t -= (unsigned long long)P_MERS;
        return (int)(t & (N_COMP - 1));
    } else {
        // int32 storage (JAX x64 off): int32 wraparound + floored mod
        unsigned int t = (unsigned int)rn0 * (unsigned int)j + (unsigned int)rn1;
        int ti = (int)t;
        int m1 = ti % P_MERS;
        if (m1 < 0) m1 += P_MERS;
        return m1 & (N_COMP - 1);
    }
}

// Single cooperative kernel: [W phase-0 DMA by all blocks] -> [xc by blocks
// 0..63, overlapped with the DMA landing] -> grid.sync -> [R14-style 8-phase
// DMA-staged MFMA gemm by all 512 blocks].
#define WT_ROWD 260                   // padded row stride in f32 (1040B, 16B-aligned)
#define WT_TILE (16 * WT_ROWD)

__global__ __launch_bounds__(512, 4) void k_fused(const float* __restrict__ x,
                                                  const float* __restrict__ W,
                                                  const int* __restrict__ rn,
                                                  unsigned int* __restrict__ xcFu,
                                                  float* __restrict__ y) {
    __shared__ float wt[2][WT_TILE];             // 2 x 16.25 KB (raw f32 W tiles)
    __shared__ float ys[8][M_ROWS][16];          // 32 KB; xc row[] overlays it
    float* row = &ys[0][0][0];                   // 2048 f32 (8 KB) scratch

    const int tid  = threadIdx.x;
    const int lane = tid & 63;
    const int w    = __builtin_amdgcn_readfirstlane(tid >> 6);  // wave 0..7
    const int nr   = lane & 15;
    const int kg   = lane >> 4;
    const int bid  = blockIdx.x;
    const int n0   = bid * 16;
    const int rot  = (bid >> 3) & 7;
    const int r0   = 2 * w;

    const float* g0 = W + (size_t)(n0 + r0) * N_COMP + lane * 4;
    const float* g1 = g0 + N_COMP;

    // ---- all blocks: issue phase-`rot` W DMA into buf 0 (independent of xc)
    GLL(g0 + rot * 256, &wt[0][r0 * WT_ROWD]);
    GLL(g1 + rot * 256, &wt[0][(r0 + 1) * WT_ROWD]);

    // ---- blocks 0..63: build compressed row m = bid, write fragment-major xcF
    if (bid < M_ROWS) {
        const int m = bid;
        row[tid] = 0.f; row[tid + 512] = 0.f;
        row[tid + 1024] = 0.f; row[tid + 1536] = 0.f;
        const int rn0 = rn[0], rn1 = rn[1], rn2 = rn[2], rn3 = rn[3];
        __syncthreads();
        const float* xm = x + (size_t)m * K_FULL;
#pragma unroll
        for (int it = 0; it < 4; ++it) {
            int j0 = tid * 4 + it * 2048;
            float4 v = *(const float4*)(xm + j0);
            atomicAdd(&row[hash_col(j0 + 0, rn0, rn1, rn2, rn3)], v.x);
            atomicAdd(&row[hash_col(j0 + 1, rn0, rn1, rn2, rn3)], v.y);
            atomicAdd(&row[hash_col(j0 + 2, rn0, rn1, rn2, rn3)], v.z);
            atomicAdd(&row[hash_col(j0 + 3, rn0, rn1, rn2, rn3)], v.w);
        }
        __syncthreads();
        const int g  = m >> 4;
        const int mr = m & 15;
#pragma unroll
        for (int q = 0; q < 2; ++q) {
            const int c0 = 2 * (tid + q * 512);
            const int s  = c0 >> 5;
            const int kq = (c0 >> 3) & 3;
            const int e0 = c0 & 7;
            xcFu[(((s * 4 + g) * 64 + kq * 16 + mr) << 2) + (e0 >> 1)] =
                pk2bf(row[c0], row[c0 + 1]);
        }
        __threadfence();   // make xcF stores device-visible before the grid barrier
    }

    cg::this_grid().sync();

    // ---- gemm: R14 structure (8 phases x 256 k, DMA double-buffer, rotation)
    const unsigned short* ab = (const unsigned short*)xcFu
                             + (size_t)w * 2048 + lane * 8;
    f32x4 acc0 = {0.f, 0.f, 0.f, 0.f};
    f32x4 acc1 = {0.f, 0.f, 0.f, 0.f};
    f32x4 acc2 = {0.f, 0.f, 0.f, 0.f};
    f32x4 acc3 = {0.f, 0.f, 0.f, 0.f};

#pragma unroll 1
    for (int p = 0; p < 8; ++p) {
        const int b  = p & 1;
        const int pm = (p + rot) & 7;        // current memory phase
        const int pn = (p + 1 + rot) & 7;    // next memory phase
        if (p < 7) {
            GLL(g0 + pn * 256, &wt[b ^ 1][r0 * WT_ROWD]);
            GLL(g1 + pn * 256, &wt[b ^ 1][(r0 + 1) * WT_ROWD]);
        }
        const unsigned short* ap = ab + (size_t)pm * 16384;
        bf16x8 a0 = *(const bf16x8*)(ap);
        bf16x8 a1 = *(const bf16x8*)(ap + 512);
        bf16x8 a2 = *(const bf16x8*)(ap + 1024);
        bf16x8 a3 = *(const bf16x8*)(ap + 1536);
        const float* bp = &wt[b][nr * WT_ROWD + w * 32 + kg * 8];
        float4 f0 = *(const float4*)(bp);
        float4 f1 = *(const float4*)(bp + 4);
        bf16x8 bf;
        bf[0] = f2bfs(f0.x); bf[1] = f2bfs(f0.y);
        bf[2] = f2bfs(f0.z); bf[3] = f2bfs(f0.w);
        bf[4] = f2bfs(f1.x); bf[5] = f2bfs(f1.y);
        bf[6] = f2bfs(f1.z); bf[7] = f2bfs(f1.w);
        acc0 = __builtin_amdgcn_mfma_f32_16x16x32_bf16(a0, bf, acc0, 0, 0, 0);
        acc1 = __builtin_amdgcn_mfma_f32_16x16x32_bf16(a1, bf, acc1, 0, 0, 0);
        acc2 = __builtin_amdgcn_mfma_f32_16x16x32_bf16(a2, bf, acc2, 0, 0, 0);
        acc3 = __builtin_amdgcn_mfma_f32_16x16x32_bf16(a3, bf, acc3, 0, 0, 0);
        __syncthreads();
    }

    // C/D layout (m89-verified): col = lane&15, row = (lane>>4)*4 + j
#pragma unroll
    for (int j = 0; j < 4; ++j) {
        ys[w][ 0 + kg * 4 + j][nr] = acc0[j];
        ys[w][16 + kg * 4 + j][nr] = acc1[j];
        ys[w][32 + kg * 4 + j][nr] = acc2[j];
        ys[w][48 + kg * 4 + j][nr] = acc3[j];
    }
    __syncthreads();

    // reduce 8 k-slices, direct store: 1024 outputs, 2 per thread
#pragma unroll
    for (int i = 0; i < 2; ++i) {
        int o = tid + 512 * i;
        int m = o >> 4;
        int n = o & 15;
        float s = 0.f;
#pragma unroll
        for (int q = 0; q < 8; ++q) s += ys[q][m][n];
        y[(size_t)m * N_OUT + n0 + n] = s;
    }
}

extern "C" void kernel_launch(void* const* d_in, const int* in_sizes, int n_in,
                              void* d_out, int out_size, void* d_ws, size_t ws_size,
                              hipStream_t stream) {
    const float* x = (const float*)d_in[0];
    const float* W = (const float*)d_in[1];
    const int* rn  = (const int*)d_in[2];
    float* y       = (float*)d_out;
    unsigned int* xcF = (unsigned int*)d_ws;

    void* args[] = { (void*)&x, (void*)&W, (void*)&rn, (void*)&xcF, (void*)&y };
    hipLaunchCooperativeKernel((const void*)k_fused, dim3(N_OUT / 16), dim3(512),
                               args, 0, stream);
}

// Round 16
// 30.504 us; speedup vs baseline: 3.3301x; 3.3301x over previous
//
#include <hip/hip_runtime.h>
#include <hip/hip_bf16.h>

// Problem constants (fixed by setup_inputs):
//   x: (64, 8192) f32   weight: (8192, 2048) f32
//   random_numbers: (4,) int (int32 or int64 storage, values in [1, 2^20))
//   y: (64, 8192) f32
#define K_FULL   8192
#define M_ROWS   64
#define N_OUT    8192
#define N_COMP   2048
#define P_MERS   2147483647

// ws layout: [0, 256KB) : xcF bf16, fragment-major:
//   xcF[(s*4 + g)*512 + lane*8 + e] = xc[g*16 + (lane&15)][s*32 + (lane>>4)*8 + e]
//   (s = k-step 0..63, g = m-group 0..3) -> every A-fragment load is 64x16B contiguous.

typedef __attribute__((ext_vector_type(8))) short bf16x8;
typedef __attribute__((ext_vector_type(4))) float f32x4;

__device__ __forceinline__ short f2bfs(float f) {
    __hip_bfloat16 h = __float2bfloat16(f);
    return *reinterpret_cast<short*>(&h);
}
__device__ __forceinline__ unsigned int pk2bf(float a, float b) {
    return (unsigned int)(unsigned short)f2bfs(a)
         | ((unsigned int)(unsigned short)f2bfs(b) << 16);
}

// Async global->LDS DMA, 16B per lane (dest = wave-uniform base + lane*16).
#define GLL(g, l) __builtin_amdgcn_global_load_lds(                          \
    (const __attribute__((address_space(1))) unsigned int*)(g),             \
    (__attribute__((address_space(3))) unsigned int*)(l), 16, 0, 0)

__device__ __forceinline__ int hash_col(int j, int rn0, int rn1, int rn2, int rn3) {
    if (rn1 == 0 && rn3 == 0) {
        // int64 storage (JAX x64 on): exact hash; Mersenne fold (2^31 === 1 mod P)
        unsigned long long xx = (unsigned long long)(unsigned int)rn0 * (unsigned int)j
                              + (unsigned long long)(unsigned int)rn2;
        unsigned long long t = (xx & (unsigned long long)P_MERS) + (xx >> 31);
        if (t >= (unsigned long long)P_MERS) t -= (unsigned long long)P_MERS;
        return (int)(t & (N_COMP - 1));
    } else {
        // int32 storage (JAX x64 off): int32 wraparound + floored mod
        unsigned int t = (unsigned int)rn0 * (unsigned int)j + (unsigned int)rn1;
        int ti = (int)t;
        int m1 = ti % P_MERS;
        if (m1 < 0) m1 += P_MERS;
        return m1 & (N_COMP - 1);
    }
}

// Fused scatter+pack: block = one m row. LDS scatter-add, then pack bf16 into
// fragment-major xcF (scattered dword writes, 4KB/block -> negligible).
__global__ __launch_bounds__(1024) void k_xc(const float* __restrict__ x,
                                             const int* __restrict__ rn,
                                             unsigned int* __restrict__ xcF) {
    __shared__ float row[N_COMP];
    const int m = blockIdx.x;
    const int tid = threadIdx.x;
    row[tid] = 0.0f;
    row[tid + 1024] = 0.0f;
    const int rn0 = rn[0], rn1 = rn[1], rn2 = rn[2], rn3 = rn[3];
    __syncthreads();

    const float* xm = x + (size_t)m * K_FULL;
#pragma unroll
    for (int it = 0; it < 2; ++it) {
        int j0 = tid * 4 + it * 4096;
        float4 v = *(const float4*)(xm + j0);
        atomicAdd(&row[hash_col(j0 + 0, rn0, rn1, rn2, rn3)], v.x);
        atomicAdd(&row[hash_col(j0 + 1, rn0, rn1, rn2, rn3)], v.y);
        atomicAdd(&row[hash_col(j0 + 2, rn0, rn1, rn2, rn3)], v.z);
        atomicAdd(&row[hash_col(j0 + 3, rn0, rn1, rn2, rn3)], v.w);
    }
    __syncthreads();

    // pack c0=2*tid, c0+1 (same s,kg; adjacent e -> one dword)
    const int c0 = 2 * tid;
    const int s  = c0 >> 5;
    const int kg = (c0 >> 3) & 3;
    const int e0 = c0 & 7;
    const int g  = m >> 4;
    const int nr = m & 15;
    xcF[(((s * 4 + g) * 64 + kg * 16 + nr) << 2) + (e0 >> 1)] =
        pk2bf(row[c0], row[c0 + 1]);
}

// MFMA GEMM v11 = R14 + counted-vmcnt barriers (T4): the per-phase
// __syncthreads (which drains vmcnt to 0, killing the DMA double-buffer)
// is replaced by `s_waitcnt vmcnt(6)` + raw s_barrier: the 2 next-phase
// DMAs stay in flight across the barrier; only the previous phase's DMAs
// (oldest in the queue) are guaranteed landed. Issue order per phase:
// [A-loads x4, GLL x2] so waiting-to-6 targets exactly the old DMAs.
// ys overlays the wt tiles (both 32KB-class, barrier-separated).
#define WT_ROWD 260                   // padded row stride in f32 (1040B, 16B-aligned)
#define WT_TILE (16 * WT_ROWD)        // 4160 f32 per buffer

__global__ __launch_bounds__(512) void k_gemm(const float* __restrict__ W,
                                              const unsigned short* __restrict__ xcF,
                                              float* __restrict__ y) {
    __shared__ float smem[2 * WT_TILE];          // 33.3 KB: wt[2]; ys overlays
    const int tid  = threadIdx.x;
    const int lane = tid & 63;
    const int w    = __builtin_amdgcn_readfirstlane(tid >> 6);  // wave 0..7
    const int nr   = lane & 15;
    const int kg   = lane >> 4;
    const int n0   = blockIdx.x * 16;
    const int rot  = (blockIdx.x >> 3) & 7;
    const int r0   = 2 * w;                      // rows staged by this wave

    const float* g0 = W + (size_t)(n0 + r0) * N_COMP + lane * 4;
    const float* g1 = g0 + N_COMP;
    const unsigned short* ab = xcF + (size_t)w * 2048 + lane * 8;

    f32x4 acc0 = {0.f, 0.f, 0.f, 0.f};
    f32x4 acc1 = {0.f, 0.f, 0.f, 0.f};
    f32x4 acc2 = {0.f, 0.f, 0.f, 0.f};
    f32x4 acc3 = {0.f, 0.f, 0.f, 0.f};

    // ---- prologue: DMA phase `rot` into buf 0 (no wait here)
    GLL(g0 + rot * 256, &smem[r0 * WT_ROWD]);
    GLL(g1 + rot * 256, &smem[(r0 + 1) * WT_ROWD]);

#pragma unroll 1
    for (int p = 0; p < 8; ++p) {
        const int b  = p & 1;
        const int pm = (p + rot) & 7;        // current memory phase
        const int pn = (p + 1 + rot) & 7;    // next memory phase
        // A fragments for k-step s = pm*8 + w -- issued FIRST (older than GLLs)
        const unsigned short* ap = ab + (size_t)pm * 16384;
        bf16x8 a0 = *(const bf16x8*)(ap);
        bf16x8 a1 = *(const bf16x8*)(ap + 512);
        bf16x8 a2 = *(const bf16x8*)(ap + 1024);
        bf16x8 a3 = *(const bf16x8*)(ap + 1536);
        asm volatile("" ::: "memory");       // pin A-loads before the GLLs
        if (p < 7) {
            GLL(g0 + pn * 256, &smem[(b ^ 1) * WT_TILE + r0 * WT_ROWD]);
            GLL(g1 + pn * 256, &smem[(b ^ 1) * WT_TILE + (r0 + 1) * WT_ROWD]);
            // outstanding: [prevGLL x2][A x4][newGLL x2] -> wait to 6 lands prevGLL
            asm volatile("s_waitcnt vmcnt(6)" ::: "memory");
        } else {
            // outstanding: [prevGLL x2][A x4] -> wait to 4 lands prevGLL
            asm volatile("s_waitcnt vmcnt(4)" ::: "memory");
        }
        __builtin_amdgcn_s_barrier();        // tile b fully written, cross-wave
        __builtin_amdgcn_sched_barrier(0);
        // B fragment: 8 f32 from LDS row nr, k-local = w*32 + kg*8
        const float* bp = &smem[b * WT_TILE + nr * WT_ROWD + w * 32 + kg * 8];
        float4 f0 = *(const float4*)(bp);
        float4 f1 = *(const float4*)(bp + 4);
        bf16x8 bf;
        bf[0] = f2bfs(f0.x); bf[1] = f2bfs(f0.y);
        bf[2] = f2bfs(f0.z); bf[3] = f2bfs(f0.w);
        bf[4] = f2bfs(f1.x); bf[5] = f2bfs(f1.y);
        bf[6] = f2bfs(f1.z); bf[7] = f2bfs(f1.w);
        acc0 = __builtin_amdgcn_mfma_f32_16x16x32_bf16(a0, bf, acc0, 0, 0, 0);
        acc1 = __builtin_amdgcn_mfma_f32_16x16x32_bf16(a1, bf, acc1, 0, 0, 0);
        acc2 = __builtin_amdgcn_mfma_f32_16x16x32_bf16(a2, bf, acc2, 0, 0, 0);
        acc3 = __builtin_amdgcn_mfma_f32_16x16x32_bf16(a3, bf, acc3, 0, 0, 0);
        // NOTE: no end-of-phase barrier; next iteration's barrier covers the
        // buf swap, and tile b^1 is only read after that barrier confirms it.
        __builtin_amdgcn_s_barrier();        // protect buf b from early rewrite
    }

    __syncthreads();   // full drain before ys overlays the W tiles

    // ---- epilogue: ys overlays smem
    float (*ys)[M_ROWS][16] = (float (*)[M_ROWS][16])smem;
    // C/D layout (m89-verified): col = lane&15, row = (lane>>4)*4 + j
#pragma unroll
    for (int j = 0; j < 4; ++j) {
        ys[w][ 0 + kg * 4 + j][nr] = acc0[j];
        ys[w][16 + kg * 4 + j][nr] = acc1[j];
        ys[w][32 + kg * 4 + j][nr] = acc2[j];
        ys[w][48 + kg * 4 + j][nr] = acc3[j];
    }
    __syncthreads();

    // reduce 8 k-slices, direct store: 1024 outputs, 2 per thread
#pragma unroll
    for (int i = 0; i < 2; ++i) {
        int o = tid + 512 * i;
        int m = o >> 4;
        int n = o & 15;
        float s = 0.f;
#pragma unroll
        for (int q = 0; q < 8; ++q) s += ys[q][m][n];
        y[(size_t)m * N_OUT + n0 + n] = s;
    }
}

extern "C" void kernel_launch(void* const* d_in, const int* in_sizes, int n_in,
                              void* d_out, int out_size, void* d_ws, size_t ws_size,
                              hipStream_t stream) {
    const float* x = (const float*)d_in[0];
    const float* W = (const float*)d_in[1];
    const int* rn  = (const int*)d_in[2];
    float* y       = (float*)d_out;

    unsigned int* xcF = (unsigned int*)d_ws;

    k_xc<<<M_ROWS, 1024, 0, stream>>>(x, rn, xcF);
    k_gemm<<<N_OUT / 16, 512, 0, stream>>>(W, (const unsigned short*)xcF, y);
}